// Round 8
// baseline (4007.532 us; speedup 1.0000x reference)
//
#include <hip/hip_runtime.h>
#include <math.h>

#define Bn   2048
#define Hd   512
#define H3   1536
#define OUTD 256
#define Nn   32768
#define TMAX 48
#define Kd   512

typedef __attribute__((ext_vector_type(8))) short short8v;
typedef __attribute__((ext_vector_type(4))) float float4v;

__device__ __forceinline__ float sigm(float x) { return 1.0f / (1.0f + __expf(-x)); }

__device__ __forceinline__ short f2bf(float v) {
    union { float f; unsigned u; } a; a.f = v;
    unsigned r = a.u + 0x7fffu + ((a.u >> 16) & 1u);
    return (short)(r >> 16);
}
__device__ __forceinline__ float bf2f(short s) {
    union { float f; unsigned u; } a; a.u = ((unsigned)(unsigned short)s) << 16;
    return a.f;
}

#define MF(acc, A, B) acc = __builtin_amdgcn_mfma_f32_16x16x32_bf16(A, B, acc, 0, 0, 0)

// ---------- prologue: counts/starts + count-descending sort + active[] ----------
__global__ void prologue(const int* __restrict__ psi, int* __restrict__ perm,
                         int* __restrict__ startsP, int* __restrict__ active) {
    __shared__ int hist[64];
    __shared__ int base[64];
    __shared__ int cur[64];
    __shared__ int cnt_s[Bn];
    __shared__ int start_s[Bn];
    const int tid = threadIdx.x;
    if (tid < 64) { hist[tid] = 0; cur[tid] = 0; }
    __syncthreads();
    for (int b = tid; b < Bn; b += 1024) {
        int lo = 0, hi = Nn;
        while (lo < hi) { int mid = (lo + hi) >> 1; if (psi[mid] < b) lo = mid + 1; else hi = mid; }
        int lb = lo;
        lo = 0; hi = Nn;
        while (lo < hi) { int mid = (lo + hi) >> 1; if (psi[mid] <= b) lo = mid + 1; else hi = mid; }
        int c = lo - lb;
        cnt_s[b] = c;
        start_s[b] = lb;
        atomicAdd(&hist[min(c, 63)], 1);
    }
    __syncthreads();
    if (tid == 0) {
        base[63] = 0;
        for (int c = 62; c >= 0; --c) base[c] = base[c + 1] + hist[c + 1];
    }
    __syncthreads();
    if (tid < 64) active[tid] = base[tid];
    for (int b = tid; b < Bn; b += 1024) {
        int c = min(cnt_s[b], 63);
        int pos = base[c] + atomicAdd(&cur[c], 1);
        perm[pos] = b;
        startsP[pos] = start_s[b];
    }
}

// ---------- split fp32 -> bf16 hi + lo ----------
__global__ __launch_bounds__(256)
void split_kern(const float* __restrict__ src, short* __restrict__ hi,
                short* __restrict__ lo, int n) {
    int i = (blockIdx.x * 256 + threadIdx.x) * 4;
    if (i >= n) return;
    float4 v = *(const float4*)&src[i];
    float vv[4] = {v.x, v.y, v.z, v.w};
    short h4[4], l4[4];
    #pragma unroll
    for (int c = 0; c < 4; ++c) {
        short h = f2bf(vv[c]);
        h4[c] = h;
        l4[c] = f2bf(vv[c] - bf2f(h));
    }
    *(short4*)&hi[i] = make_short4(h4[0], h4[1], h4[2], h4[3]);
    *(short4*)&lo[i] = make_short4(l4[0], l4[1], l4[2], l4[3]);
}

// split x rows permuted into compact order
__global__ __launch_bounds__(256)
void split_perm(const float* __restrict__ src, const int* __restrict__ perm,
                short* __restrict__ hi, short* __restrict__ lo) {
    int i = (blockIdx.x * 256 + threadIdx.x) * 4;       // over 2048*512
    int row = i >> 9, col = i & 511;
    int srow = perm[row];
    float4 v = *(const float4*)&src[(size_t)srow * 512 + col];
    float vv[4] = {v.x, v.y, v.z, v.w};
    short h4[4], l4[4];
    #pragma unroll
    for (int c = 0; c < 4; ++c) {
        short h = f2bf(vv[c]);
        h4[c] = h;
        l4[c] = f2bf(vv[c] - bf2f(h));
    }
    *(short4*)&hi[i] = make_short4(h4[0], h4[1], h4[2], h4[3]);
    *(short4*)&lo[i] = make_short4(l4[0], l4[1], l4[2], l4[3]);
}

// pack W1rz[1024][1024] = [Wih1_rz | Whh1_rz] split hi/lo
__global__ __launch_bounds__(256)
void pack_w1rz(const float* __restrict__ Wih1, const float* __restrict__ Whh1,
               short* __restrict__ hi, short* __restrict__ lo) {
    int i = (blockIdx.x * 256 + threadIdx.x) * 4;       // over 1024*1024
    int orow = i >> 10, k = i & 1023;
    const float* s = (k < 512) ? &Wih1[(size_t)orow * 512 + k]
                               : &Whh1[(size_t)orow * 512 + (k - 512)];
    float4 v = *(const float4*)s;
    float vv[4] = {v.x, v.y, v.z, v.w};
    short h4[4], l4[4];
    #pragma unroll
    for (int c = 0; c < 4; ++c) {
        short h = f2bf(vv[c]);
        h4[c] = h;
        l4[c] = f2bf(vv[c] - bf2f(h));
    }
    *(short4*)&hi[i] = make_short4(h4[0], h4[1], h4[2], h4[3]);
    *(short4*)&lo[i] = make_short4(l4[0], l4[1], l4[2], l4[3]);
}

__global__ __launch_bounds__(256)
void zero4(short* __restrict__ a, short* __restrict__ b,
           short* __restrict__ c, short* __restrict__ d, int n) {
    int i = (blockIdx.x * 256 + threadIdx.x) * 4;
    if (i >= n) return;
    short4 z = make_short4(0, 0, 0, 0);
    *(short4*)&a[i] = z; *(short4*)&b[i] = z;
    *(short4*)&c[i] = z; *(short4*)&d[i] = z;
}

// ---------- MFMA 128x128 tile core (round-5 proven): C = A @ W^T (+bias) ----------
template<bool SPLIT_A>
__device__ __forceinline__ void gemm_tile(
    const short* __restrict__ Ahi, const short* __restrict__ Alo,
    const short* __restrict__ Whi, const short* __restrict__ Wlo,
    const float* __restrict__ bias, float* __restrict__ C,
    int m0, int n0, int ldC, short* lds) {
    short* ldsAhi = lds;
    short* ldsAlo = lds + 4096;
    short* ldsBhi = lds + 8192;
    short* ldsBlo = lds + 12288;
    const int tid = threadIdx.x;
    const int wid = tid >> 6, lane = tid & 63;
    const int wm = wid >> 1, wn = wid & 1;
    const int oi0 = tid * 2, oi1 = tid * 2 + 1;
    const int r0 = oi0 >> 2, c0 = oi0 & 3;
    const int r1 = oi1 >> 2, c1 = oi1 & 3;
    const int w0 = ((r0 >> 4) * 64 + (r0 & 15) + (c0 << 4)) * 8;
    const int w1 = ((r1 >> 4) * 64 + (r1 & 15) + (c1 << 4)) * 8;

    float4v acc[4][4] = {};
    int4 ah0, ah1, al0, al1, bh0, bh1, bl0, bl1;

#define LOADK(kt) do { const int k0 = (kt) * 32; \
    ah0 = *(const int4*)&Ahi[(size_t)(m0 + r0) * Kd + k0 + c0 * 8]; \
    ah1 = *(const int4*)&Ahi[(size_t)(m0 + r1) * Kd + k0 + c1 * 8]; \
    if constexpr (SPLIT_A) { \
        al0 = *(const int4*)&Alo[(size_t)(m0 + r0) * Kd + k0 + c0 * 8]; \
        al1 = *(const int4*)&Alo[(size_t)(m0 + r1) * Kd + k0 + c1 * 8]; } \
    bh0 = *(const int4*)&Whi[(size_t)(n0 + r0) * Kd + k0 + c0 * 8]; \
    bh1 = *(const int4*)&Whi[(size_t)(n0 + r1) * Kd + k0 + c1 * 8]; \
    bl0 = *(const int4*)&Wlo[(size_t)(n0 + r0) * Kd + k0 + c0 * 8]; \
    bl1 = *(const int4*)&Wlo[(size_t)(n0 + r1) * Kd + k0 + c1 * 8]; } while (0)

    LOADK(0);
    for (int kt = 0; kt < 16; ++kt) {
        __syncthreads();
        *(int4*)&ldsAhi[w0] = ah0; *(int4*)&ldsAhi[w1] = ah1;
        if constexpr (SPLIT_A) { *(int4*)&ldsAlo[w0] = al0; *(int4*)&ldsAlo[w1] = al1; }
        *(int4*)&ldsBhi[w0] = bh0; *(int4*)&ldsBhi[w1] = bh1;
        *(int4*)&ldsBlo[w0] = bl0; *(int4*)&ldsBlo[w1] = bl1;
        __syncthreads();
        if (kt < 15) LOADK(kt + 1);
        short8v afh[4], afl[4], bfh[4], bfl[4];
        #pragma unroll
        for (int mi = 0; mi < 4; ++mi) {
            afh[mi] = *(const short8v*)&ldsAhi[((wm * 4 + mi) * 64 + lane) * 8];
            if constexpr (SPLIT_A)
                afl[mi] = *(const short8v*)&ldsAlo[((wm * 4 + mi) * 64 + lane) * 8];
        }
        #pragma unroll
        for (int ni = 0; ni < 4; ++ni) {
            bfh[ni] = *(const short8v*)&ldsBhi[((wn * 4 + ni) * 64 + lane) * 8];
            bfl[ni] = *(const short8v*)&ldsBlo[((wn * 4 + ni) * 64 + lane) * 8];
        }
        #pragma unroll
        for (int mi = 0; mi < 4; ++mi)
            #pragma unroll
            for (int ni = 0; ni < 4; ++ni) {
                MF(acc[mi][ni], afh[mi], bfh[ni]);
                MF(acc[mi][ni], afh[mi], bfl[ni]);
                if constexpr (SPLIT_A) MF(acc[mi][ni], afl[mi], bfh[ni]);
            }
    }
#undef LOADK
    #pragma unroll
    for (int mi = 0; mi < 4; ++mi) {
        #pragma unroll
        for (int ni = 0; ni < 4; ++ni) {
            int row = m0 + wm * 64 + mi * 16 + ((lane >> 4) << 2);
            int col = n0 + wn * 64 + ni * 16 + (lane & 15);
            float bv = bias ? bias[col] : 0.0f;
            #pragma unroll
            for (int r = 0; r < 4; ++r)
                C[(size_t)(row + r) * ldC + col] = acc[mi][ni][r] + bv;
        }
    }
}

template<bool SPLIT_A>
__global__ __launch_bounds__(256)
void gemm_one(const short* __restrict__ Ahi, const short* __restrict__ Alo,
              const short* __restrict__ Whi, const short* __restrict__ Wlo,
              const float* __restrict__ bias, float* __restrict__ C, int ntn) {
    __shared__ short lds[16384];
    int m0 = (blockIdx.x / ntn) * 128, n0 = (blockIdx.x % ntn) * 128;
    gemm_tile<SPLIT_A>(Ahi, Alo, Whi, Wlo, bias, C, m0, n0, ntn * 128, lds);
}

// ================= fused GRU step (wide tiles, weight-resident XCD mapping) =================
// State A[2048][1024] = [h0|h1] bf16 hi/lo, ping-pong.
// bb in [0,128): layer-0, 128 rows x 64 cols (3 gates), K=512.  bb = mb*8 + js -> XCD = js.
// bb in [128,384): layer-1, 64 rows x 64 cols, rz K=1024 + Xn/Hn K=512. bb-128 = mb2*8 + js.
// Each XCD's L2 holds only its js weight slice (~1.15MB) -> resident across iterations.
__global__ __launch_bounds__(256, 2)
void fused_step(const short* __restrict__ OLDhi, const short* __restrict__ OLDlo,
                short* __restrict__ NEWhi, short* __restrict__ NEWlo,
                const short* __restrict__ W0hi, const short* __restrict__ W0lo,
                const short* __restrict__ Wrzhi, const short* __restrict__ Wrzlo,
                const short* __restrict__ Wnxhi, const short* __restrict__ Wnxlo,
                const short* __restrict__ Wnhhi, const short* __restrict__ Wnhlo,
                const float* __restrict__ xp0P, const float* __restrict__ bhh0,
                const float* __restrict__ bih1, const float* __restrict__ bhh1,
                short* __restrict__ sel_h, const int* __restrict__ startsP,
                const int* __restrict__ active, int i) {
    __shared__ short lds[20480];          // A: [0,8192) (hi 0, lo 4096); panels: [8192,20480)
    short* ldsA = lds;
    short* ldsP = lds + 8192;             // 6 panel-halves x 2048 shorts
    const int tid = threadIdx.x;
    const int bb = blockIdx.x;
    const int wid = tid >> 6, lane = tid & 63;
    const int wm = wid >> 1, wn = wid & 1;

    if (bb < 128) {
        // ---------------- layer-0: rows m0..m0+128, gate-cols j0..j0+64, K=512 ----------------
        const int act = active[i];
        const int mb = bb >> 3, js = bb & 7;
        const int m0 = mb * 128, j0 = js * 64;
        if (m0 >= act) return;

        // A staging: 4 int4/thread (128 rows x 4 oct x 2 halves)
        int aOff[4]; const short* aSrc[4];
        #pragma unroll
        for (int rep = 0; rep < 4; ++rep) {
            int u = rep * 256 + tid;
            int half = u >> 9, wi = u & 511;
            int ar = wi >> 2, ac = wi & 3;
            aOff[rep] = half * 4096 + ((ar >> 4) * 64 + (ar & 15) + (ac << 4)) * 8;
            aSrc[rep] = (half ? OLDlo : OLDhi) + (size_t)(m0 + ar) * 1024 + ac * 8;
        }
        // panel staging: 6 int4/thread (6 panel-halves x 64 rows x 4 oct)
        int pOff[6]; const short* pSrc[6];
        #pragma unroll
        for (int rep = 0; rep < 6; ++rep) {
            int u = rep * 256 + tid;
            int p = u >> 8, wi = u & 255;
            int pr = wi >> 2, pc = wi & 3;
            pOff[rep] = p * 2048 + ((pr >> 4) * 64 + (pr & 15) + (pc << 4)) * 8;
            int g = p >> 1, hl = p & 1;
            pSrc[rep] = (hl ? W0lo : W0hi) + (size_t)(g * 512 + j0 + pr) * 512 + pc * 8;
        }

        float4v aR[4][2] = {}, aZ[4][2] = {}, aN[4][2] = {};
        int4 av[4], pv[6];
        auto LOAD = [&](int kt) {
            const int k0 = kt * 32;
            #pragma unroll
            for (int rep = 0; rep < 4; ++rep) av[rep] = *(const int4*)(aSrc[rep] + k0);
            #pragma unroll
            for (int rep = 0; rep < 6; ++rep) pv[rep] = *(const int4*)(pSrc[rep] + k0);
        };
        LOAD(0);
        for (int kt = 0; kt < 16; ++kt) {
            __syncthreads();
            #pragma unroll
            for (int rep = 0; rep < 4; ++rep) *(int4*)&ldsA[aOff[rep]] = av[rep];
            #pragma unroll
            for (int rep = 0; rep < 6; ++rep) *(int4*)&ldsP[pOff[rep]] = pv[rep];
            __syncthreads();
            if (kt < 15) LOAD(kt + 1);
            short8v afh[4], afl[4];
            #pragma unroll
            for (int mi = 0; mi < 4; ++mi) {
                afh[mi] = *(const short8v*)&ldsA[((wm * 4 + mi) * 64 + lane) * 8];
                afl[mi] = *(const short8v*)&ldsA[4096 + ((wm * 4 + mi) * 64 + lane) * 8];
            }
            #pragma unroll
            for (int ni = 0; ni < 2; ++ni) {
                {   short8v bh = *(const short8v*)&ldsP[0 * 2048 + ((wn * 2 + ni) * 64 + lane) * 8];
                    short8v bl = *(const short8v*)&ldsP[1 * 2048 + ((wn * 2 + ni) * 64 + lane) * 8];
                    #pragma unroll
                    for (int mi = 0; mi < 4; ++mi) { MF(aR[mi][ni], afh[mi], bh); MF(aR[mi][ni], afh[mi], bl); MF(aR[mi][ni], afl[mi], bh); } }
                {   short8v bh = *(const short8v*)&ldsP[2 * 2048 + ((wn * 2 + ni) * 64 + lane) * 8];
                    short8v bl = *(const short8v*)&ldsP[3 * 2048 + ((wn * 2 + ni) * 64 + lane) * 8];
                    #pragma unroll
                    for (int mi = 0; mi < 4; ++mi) { MF(aZ[mi][ni], afh[mi], bh); MF(aZ[mi][ni], afh[mi], bl); MF(aZ[mi][ni], afl[mi], bh); } }
                {   short8v bh = *(const short8v*)&ldsP[4 * 2048 + ((wn * 2 + ni) * 64 + lane) * 8];
                    short8v bl = *(const short8v*)&ldsP[5 * 2048 + ((wn * 2 + ni) * 64 + lane) * 8];
                    #pragma unroll
                    for (int mi = 0; mi < 4; ++mi) { MF(aN[mi][ni], afh[mi], bh); MF(aN[mi][ni], afh[mi], bl); MF(aN[mi][ni], afl[mi], bh); } }
            }
        }
        #pragma unroll
        for (int ni = 0; ni < 2; ++ni) {
            const int col = j0 + wn * 32 + ni * 16 + (lane & 15);
            const float b_r = bhh0[col], b_z = bhh0[512 + col], b_n = bhh0[1024 + col];
            #pragma unroll
            for (int mi = 0; mi < 4; ++mi) {
                int rowb = m0 + wm * 64 + mi * 16 + ((lane >> 4) << 2);
                #pragma unroll
                for (int r = 0; r < 4; ++r) {
                    int row = rowb + r;
                    float xr = xp0P[(size_t)row * H3 + col];
                    float xz = xp0P[(size_t)row * H3 + 512 + col];
                    float xn = xp0P[(size_t)row * H3 + 1024 + col];
                    float rr = sigm(xr + aR[mi][ni][r] + b_r);
                    float zz = sigm(xz + aZ[mi][ni][r] + b_z);
                    float nn = tanhf(xn + rr * (aN[mi][ni][r] + b_n));
                    float hp = bf2f(OLDhi[(size_t)row * 1024 + col]) + bf2f(OLDlo[(size_t)row * 1024 + col]);
                    float h = (1.0f - zz) * nn + zz * hp;
                    short hh = f2bf(h);
                    NEWhi[(size_t)row * 1024 + col] = hh;
                    NEWlo[(size_t)row * 1024 + col] = f2bf(h - bf2f(hh));
                }
            }
        }
    } else {
        // ---------------- layer-1: rows m0..m0+64, cols j0..j0+64 ----------------
        if (i < 1) return;
        const int act = active[i - 1];
        const int idx = bb - 128;
        const int mb = idx >> 3, js = idx & 7;
        const int m0 = mb * 64, j0 = js * 64;
        if (m0 >= act) return;
        const int t = i - 1;

        // A staging: 2 int4/thread (64 rows x 4 oct x 2 halves)
        int aOff[2]; const short* aSrc[2];
        #pragma unroll
        for (int rep = 0; rep < 2; ++rep) {
            int u = rep * 256 + tid;
            int half = u >> 8, wi = u & 255;
            int ar = wi >> 2, ac = wi & 3;
            aOff[rep] = half * 4096 + ((ar >> 4) * 64 + (ar & 15) + (ac << 4)) * 8;
            aSrc[rep] = (half ? OLDlo : OLDhi) + (size_t)(m0 + ar) * 1024 + ac * 8;
        }
        // panels: pA = RZ-or-Nx (k0 in [0,512)), pB = RZ-or-(Nh shifted) (k0 in [512,1024))
        int pOff[6]; const short* pA[6]; const short* pB[6];
        #pragma unroll
        for (int rep = 0; rep < 6; ++rep) {
            int u = rep * 256 + tid;
            int p = u >> 8, wi = u & 255;
            int pr = wi >> 2, pc = wi & 3;
            pOff[rep] = p * 2048 + ((pr >> 4) * 64 + (pr & 15) + (pc << 4)) * 8;
            int g = p >> 1, hl = p & 1;
            const short* Wrz = hl ? Wrzlo : Wrzhi;
            const short* Wx  = hl ? Wnxlo : Wnxhi;
            const short* Wh  = hl ? Wnhlo : Wnhhi;
            const short* rz = Wrz + (size_t)(min(g, 1) * 512 + j0 + pr) * 1024 + pc * 8;
            pA[rep] = (g < 2) ? rz : (Wx + (size_t)(j0 + pr) * 512 + pc * 8);
            pB[rep] = (g < 2) ? rz : (Wh + (size_t)(j0 + pr) * 512 + pc * 8 - 512);
        }

        float4v aR[2][2] = {}, aZ[2][2] = {}, aXn[2][2] = {}, aHn[2][2] = {};
        int4 av[2], pv[6];
        auto LOAD1 = [&](int kt) {
            const int k0 = kt * 32;
            #pragma unroll
            for (int rep = 0; rep < 2; ++rep) av[rep] = *(const int4*)(aSrc[rep] + k0);
            #pragma unroll
            for (int rep = 0; rep < 6; ++rep) pv[rep] = *(const int4*)(pA[rep] + k0);
        };
        auto LOAD2 = [&](int kt) {
            const int k0 = kt * 32;
            #pragma unroll
            for (int rep = 0; rep < 2; ++rep) av[rep] = *(const int4*)(aSrc[rep] + k0);
            #pragma unroll
            for (int rep = 0; rep < 6; ++rep) pv[rep] = *(const int4*)(pB[rep] + k0);
        };

#define STAGE() do { \
    __syncthreads(); \
    _Pragma("unroll") for (int rep = 0; rep < 2; ++rep) *(int4*)&ldsA[aOff[rep]] = av[rep]; \
    _Pragma("unroll") for (int rep = 0; rep < 6; ++rep) *(int4*)&ldsP[pOff[rep]] = pv[rep]; \
    __syncthreads(); } while (0)

#define AFR \
    short8v afh[2], afl[2]; \
    _Pragma("unroll") for (int mi = 0; mi < 2; ++mi) { \
        afh[mi] = *(const short8v*)&ldsA[((wm * 2 + mi) * 64 + lane) * 8]; \
        afl[mi] = *(const short8v*)&ldsA[4096 + ((wm * 2 + mi) * 64 + lane) * 8]; }

#define GB(ACC, P) { \
    short8v bh = *(const short8v*)&ldsP[(P) * 4096 + ((wn * 2 + ni) * 64 + lane) * 8]; \
    short8v bl = *(const short8v*)&ldsP[(P) * 4096 + 2048 + ((wn * 2 + ni) * 64 + lane) * 8]; \
    _Pragma("unroll") for (int mi = 0; mi < 2; ++mi) { \
        MF(ACC[mi][ni], afh[mi], bh); MF(ACC[mi][ni], afh[mi], bl); MF(ACC[mi][ni], afl[mi], bh); } }

        LOAD1(0);
        for (int kt = 0; kt < 16; ++kt) {
            STAGE();
            if (kt < 15) LOAD1(kt + 1); else LOAD2(16);
            AFR
            #pragma unroll
            for (int ni = 0; ni < 2; ++ni) { GB(aR, 0) GB(aZ, 1) GB(aXn, 2) }
        }
        for (int kt = 16; kt < 32; ++kt) {
            STAGE();
            if (kt < 31) LOAD2(kt + 1);
            AFR
            #pragma unroll
            for (int ni = 0; ni < 2; ++ni) { GB(aR, 0) GB(aZ, 1) GB(aHn, 2) }
        }
#undef STAGE
#undef AFR
#undef GB
        #pragma unroll
        for (int ni = 0; ni < 2; ++ni) {
            const int col = j0 + wn * 32 + ni * 16 + (lane & 15);
            const float b_r = bih1[col] + bhh1[col];
            const float b_z = bih1[512 + col] + bhh1[512 + col];
            const float b_xn = bih1[1024 + col];
            const float b_hn = bhh1[1024 + col];
            #pragma unroll
            for (int mi = 0; mi < 2; ++mi) {
                int rowb = m0 + wm * 32 + mi * 16 + ((lane >> 4) << 2);
                #pragma unroll
                for (int r = 0; r < 4; ++r) {
                    int row = rowb + r;
                    float rr = sigm(aR[mi][ni][r] + b_r);
                    float zz = sigm(aZ[mi][ni][r] + b_z);
                    float nn = tanhf(aXn[mi][ni][r] + b_xn + rr * (aHn[mi][ni][r] + b_hn));
                    float hp = bf2f(OLDhi[(size_t)row * 1024 + 512 + col]) + bf2f(OLDlo[(size_t)row * 1024 + 512 + col]);
                    float h = (1.0f - zz) * nn + zz * hp;
                    short hh = f2bf(h);
                    NEWhi[(size_t)row * 1024 + 512 + col] = hh;
                    NEWlo[(size_t)row * 1024 + 512 + col] = f2bf(h - bf2f(hh));
                    if (row < act)
                        sel_h[((size_t)startsP[row] + t) * Hd + col] = f2bf(h);
                }
            }
        }
    }
}

extern "C" void kernel_launch(void* const* d_in, const int* in_sizes, int n_in,
                              void* d_out, int out_size, void* d_ws, size_t ws_size,
                              hipStream_t stream) {
    (void)in_sizes; (void)n_in; (void)out_size; (void)ws_size;
    const float* x    = (const float*)d_in[0];
    const float* Wih0 = (const float*)d_in[1];
    const float* Whh0 = (const float*)d_in[2];
    const float* bih0 = (const float*)d_in[3];
    const float* bhh0 = (const float*)d_in[4];
    const float* Wih1 = (const float*)d_in[5];
    const float* Whh1 = (const float*)d_in[6];
    const float* bih1 = (const float*)d_in[7];
    const float* bhh1 = (const float*)d_in[8];
    const float* Wout = (const float*)d_in[9];
    const float* bout = (const float*)d_in[10];
    const int*   psi  = (const int*)d_in[11];
    float* out = (float*)d_out;

    char* p = (char*)d_ws;
    auto alloc = [&](size_t bytes) { char* r = p; p += (bytes + 255) & ~255ULL; return r; };
    short* xPhi   = (short*)alloc((size_t)Bn * Kd * 2);
    short* xPlo   = (short*)alloc((size_t)Bn * Kd * 2);
    short* Wih0hi = (short*)alloc((size_t)H3 * Kd * 2);
    short* Wih0lo = (short*)alloc((size_t)H3 * Kd * 2);
    short* W0hi   = (short*)alloc((size_t)H3 * Kd * 2);
    short* W0lo   = (short*)alloc((size_t)H3 * Kd * 2);
    short* Wrzhi  = (short*)alloc((size_t)1024 * 1024 * 2);
    short* Wrzlo  = (short*)alloc((size_t)1024 * 1024 * 2);
    short* Wnxhi  = (short*)alloc((size_t)512 * 512 * 2);
    short* Wnxlo  = (short*)alloc((size_t)512 * 512 * 2);
    short* Wnhhi  = (short*)alloc((size_t)512 * 512 * 2);
    short* Wnhlo  = (short*)alloc((size_t)512 * 512 * 2);
    short* Wouthi = (short*)alloc((size_t)OUTD * Kd * 2);
    short* Woutlo = (short*)alloc((size_t)OUTD * Kd * 2);
    float* xp0P   = (float*)alloc((size_t)Bn * H3 * 4);
    short* Aahi   = (short*)alloc((size_t)Bn * 1024 * 2);
    short* Aalo   = (short*)alloc((size_t)Bn * 1024 * 2);
    short* Abhi   = (short*)alloc((size_t)Bn * 1024 * 2);
    short* Ablo   = (short*)alloc((size_t)Bn * 1024 * 2);
    short* sel_h  = (short*)alloc((size_t)Nn * Hd * 2);
    int* perm     = (int*)alloc(Bn * 4);
    int* startsP  = (int*)alloc(Bn * 4);
    int* active   = (int*)alloc(64 * 4);

    prologue<<<1, 1024, 0, stream>>>(psi, perm, startsP, active);
    split_perm<<<1024, 256, 0, stream>>>(x, perm, xPhi, xPlo);
    split_kern<<<768, 256, 0, stream>>>(Wih0, Wih0hi, Wih0lo, H3 * Kd);
    split_kern<<<768, 256, 0, stream>>>(Whh0, W0hi, W0lo, H3 * Kd);
    pack_w1rz<<<1024, 256, 0, stream>>>(Wih1, Whh1, Wrzhi, Wrzlo);
    split_kern<<<256, 256, 0, stream>>>(Wih1 + (size_t)1024 * 512, Wnxhi, Wnxlo, 512 * 512);
    split_kern<<<256, 256, 0, stream>>>(Whh1 + (size_t)1024 * 512, Wnhhi, Wnhlo, 512 * 512);
    split_kern<<<128, 256, 0, stream>>>(Wout, Wouthi, Woutlo, OUTD * Kd);
    zero4<<<2048, 256, 0, stream>>>(Aahi, Aalo, Abhi, Ablo, Bn * 1024);

    gemm_one<true><<<192, 256, 0, stream>>>(xPhi, xPlo, Wih0hi, Wih0lo, bih0, xp0P, 12);

    for (int i = 0; i <= TMAX; ++i) {
        const short* OLDhi = (i & 1) ? Abhi : Aahi;
        const short* OLDlo = (i & 1) ? Ablo : Aalo;
        short* NEWhi = (i & 1) ? Aahi : Abhi;
        short* NEWlo = (i & 1) ? Aalo : Ablo;
        fused_step<<<384, 256, 0, stream>>>(OLDhi, OLDlo, NEWhi, NEWlo,
                                            W0hi, W0lo, Wrzhi, Wrzlo,
                                            Wnxhi, Wnxlo, Wnhhi, Wnhlo,
                                            xp0P, bhh0, bih1, bhh1,
                                            sel_h, startsP, active, i);
    }

    gemm_one<false><<<512, 256, 0, stream>>>(sel_h, nullptr, Wouthi, Woutlo, bout, out, 2);
}

// Round 10
// 1600.387 us; speedup vs baseline: 2.5041x; 2.5041x over previous
//
#include <hip/hip_runtime.h>
#include <math.h>

#define Bn   2048
#define Hd   512
#define H3   1536
#define OUTD 256
#define Nn   32768
#define TMAX 48
#define Kd   512

typedef __attribute__((ext_vector_type(8))) short short8v;
typedef __attribute__((ext_vector_type(4))) float float4v;

__device__ __forceinline__ float sigm(float x) { return 1.0f / (1.0f + __expf(-x)); }

__device__ __forceinline__ short f2bf(float v) {
    union { float f; unsigned u; } a; a.f = v;
    unsigned r = a.u + 0x7fffu + ((a.u >> 16) & 1u);
    return (short)(r >> 16);
}
__device__ __forceinline__ float bf2f(short s) {
    union { float f; unsigned u; } a; a.u = ((unsigned)(unsigned short)s) << 16;
    return a.f;
}

#define MF(acc, A, B) acc = __builtin_amdgcn_mfma_f32_16x16x32_bf16(A, B, acc, 0, 0, 0)

// ---------- prologue: counts/starts + count-descending sort + active[] ----------
__global__ void prologue(const int* __restrict__ psi, int* __restrict__ perm,
                         int* __restrict__ startsP, int* __restrict__ active) {
    __shared__ int hist[64];
    __shared__ int base[64];
    __shared__ int cur[64];
    __shared__ int cnt_s[Bn];
    __shared__ int start_s[Bn];
    const int tid = threadIdx.x;
    if (tid < 64) { hist[tid] = 0; cur[tid] = 0; }
    __syncthreads();
    for (int b = tid; b < Bn; b += 1024) {
        int lo = 0, hi = Nn;
        while (lo < hi) { int mid = (lo + hi) >> 1; if (psi[mid] < b) lo = mid + 1; else hi = mid; }
        int lb = lo;
        lo = 0; hi = Nn;
        while (lo < hi) { int mid = (lo + hi) >> 1; if (psi[mid] <= b) lo = mid + 1; else hi = mid; }
        int c = lo - lb;
        cnt_s[b] = c;
        start_s[b] = lb;
        lmax:;
        atomicAdd(&hist[min(c, 63)], 1);
    }
    __syncthreads();
    if (tid == 0) {
        base[63] = 0;
        for (int c = 62; c >= 0; --c) base[c] = base[c + 1] + hist[c + 1];
    }
    __syncthreads();
    if (tid < 64) active[tid] = base[tid];
    for (int b = tid; b < Bn; b += 1024) {
        int c = min(cnt_s[b], 63);
        int pos = base[c] + atomicAdd(&cur[c], 1);
        perm[pos] = b;
        startsP[pos] = start_s[b];
    }
}

// ---------- split fp32 -> bf16 hi + bf16 lo ----------
__global__ __launch_bounds__(256)
void split_kern(const float* __restrict__ src, short* __restrict__ hi,
                short* __restrict__ lo, int n) {
    int i = (blockIdx.x * 256 + threadIdx.x) * 4;
    if (i >= n) return;
    float4 v = *(const float4*)&src[i];
    float vv[4] = {v.x, v.y, v.z, v.w};
    short h4[4], l4[4];
    #pragma unroll
    for (int c = 0; c < 4; ++c) {
        short h = f2bf(vv[c]);
        h4[c] = h;
        l4[c] = f2bf(vv[c] - bf2f(h));
    }
    *(short4*)&hi[i] = make_short4(h4[0], h4[1], h4[2], h4[3]);
    *(short4*)&lo[i] = make_short4(l4[0], l4[1], l4[2], l4[3]);
}

// split x rows permuted into compact order: row m of output = x[perm[m]]
__global__ __launch_bounds__(256)
void split_perm(const float* __restrict__ src, const int* __restrict__ perm,
                short* __restrict__ hi, short* __restrict__ lo) {
    int i = (blockIdx.x * 256 + threadIdx.x) * 4;       // over 2048*512
    int row = i >> 9, col = i & 511;
    int srow = perm[row];
    float4 v = *(const float4*)&src[(size_t)srow * 512 + col];
    float vv[4] = {v.x, v.y, v.z, v.w};
    short h4[4], l4[4];
    #pragma unroll
    for (int c = 0; c < 4; ++c) {
        short h = f2bf(vv[c]);
        h4[c] = h;
        l4[c] = f2bf(vv[c] - bf2f(h));
    }
    *(short4*)&hi[i] = make_short4(h4[0], h4[1], h4[2], h4[3]);
    *(short4*)&lo[i] = make_short4(l4[0], l4[1], l4[2], l4[3]);
}

__global__ __launch_bounds__(256)
void zeroh(short* __restrict__ a, short* __restrict__ b,
           short* __restrict__ c, short* __restrict__ d) {
    int i = (blockIdx.x * 256 + threadIdx.x) * 4;
    short4 z = make_short4(0, 0, 0, 0);
    *(short4*)&a[i] = z; *(short4*)&b[i] = z;
    *(short4*)&c[i] = z; *(short4*)&d[i] = z;
}

// ---------- MFMA 128x128 tile core, 8 waves (512 thr): C = A @ W^T (+bias), K=512 ----------
// Same LDS fragment-linear layout as r5; each wave owns a 64x32 sub-tile (wm=wid>>2, wn=wid&3).
// Staging: 1 int4 per matrix per thread; issue-early prefetch of tile kt+1 between barrier and MFMAs.
template<bool SPLIT_A>
__device__ __forceinline__ void gemm_tile(
    const short* __restrict__ Ahi, const short* __restrict__ Alo,
    const short* __restrict__ Whi, const short* __restrict__ Wlo,
    const float* __restrict__ bias, float* __restrict__ C,
    int m0, int n0, int ldC, short* lds) {
    short* ldsAhi = lds;
    short* ldsAlo = lds + 4096;
    short* ldsBhi = lds + 8192;
    short* ldsBlo = lds + 12288;
    const int tid = threadIdx.x;
    const int wid = tid >> 6, lane = tid & 63;
    const int wm = wid >> 2, wn = wid & 3;
    // staging: thread stages octet (row, oct): row = tid>>2 (0..127), oct = tid&3
    const int sr = tid >> 2, so = tid & 3;
    const int wOff = ((sr >> 4) * 64 + (sr & 15) + (so << 4)) * 8;   // LDS short offset

    const short* gAhi = Ahi + (size_t)(m0 + sr) * Kd + so * 8;
    const short* gAlo = SPLIT_A ? (Alo + (size_t)(m0 + sr) * Kd + so * 8) : nullptr;
    const short* gBhi = Whi + (size_t)(n0 + sr) * Kd + so * 8;
    const short* gBlo = Wlo + (size_t)(n0 + sr) * Kd + so * 8;

    float4v acc[4][2] = {};
    int4 vah, val, vbh, vbl;

#define LOADK(kt) do { const int k0 = (kt) * 32; \
    vah = *(const int4*)(gAhi + k0); \
    if constexpr (SPLIT_A) val = *(const int4*)(gAlo + k0); \
    vbh = *(const int4*)(gBhi + k0); \
    vbl = *(const int4*)(gBlo + k0); } while (0)

    LOADK(0);
    for (int kt = 0; kt < 16; ++kt) {
        __syncthreads();   // previous tile's fragment reads complete before overwrite
        *(int4*)&ldsAhi[wOff] = vah;
        if constexpr (SPLIT_A) *(int4*)&ldsAlo[wOff] = val;
        *(int4*)&ldsBhi[wOff] = vbh;
        *(int4*)&ldsBlo[wOff] = vbl;
        __syncthreads();
        if (kt < 15) LOADK(kt + 1);   // issue early: overlaps with MFMAs below
        short8v afh[4], afl[4], bfh[2], bfl[2];
        #pragma unroll
        for (int mi = 0; mi < 4; ++mi) {
            afh[mi] = *(const short8v*)&ldsAhi[((wm * 4 + mi) * 64 + lane) * 8];
            if constexpr (SPLIT_A)
                afl[mi] = *(const short8v*)&ldsAlo[((wm * 4 + mi) * 64 + lane) * 8];
        }
        #pragma unroll
        for (int ni = 0; ni < 2; ++ni) {
            bfh[ni] = *(const short8v*)&ldsBhi[((wn * 2 + ni) * 64 + lane) * 8];
            bfl[ni] = *(const short8v*)&ldsBlo[((wn * 2 + ni) * 64 + lane) * 8];
        }
        #pragma unroll
        for (int mi = 0; mi < 4; ++mi)
            #pragma unroll
            for (int ni = 0; ni < 2; ++ni) {
                MF(acc[mi][ni], afh[mi], bfh[ni]);
                MF(acc[mi][ni], afh[mi], bfl[ni]);
                if constexpr (SPLIT_A) MF(acc[mi][ni], afl[mi], bfh[ni]);
            }
    }
#undef LOADK
    // epilogue: C/D layout col=lane&15, row=(lane>>4)*4+reg
    #pragma unroll
    for (int mi = 0; mi < 4; ++mi) {
        #pragma unroll
        for (int ni = 0; ni < 2; ++ni) {
            int row = m0 + wm * 64 + mi * 16 + ((lane >> 4) << 2);
            int col = n0 + wn * 32 + ni * 16 + (lane & 15);
            float bv = bias ? bias[col] : 0.0f;
            #pragma unroll
            for (int r = 0; r < 4; ++r)
                C[(size_t)(row + r) * ldC + col] = acc[mi][ni][r] + bv;
        }
    }
}

template<bool SPLIT_A>
__global__ __launch_bounds__(512)
void gemm_one(const short* __restrict__ Ahi, const short* __restrict__ Alo,
              const short* __restrict__ Whi, const short* __restrict__ Wlo,
              const float* __restrict__ bias, float* __restrict__ C, int ntn) {
    __shared__ short lds[16384];
    int m0 = (blockIdx.x / ntn) * 128, n0 = (blockIdx.x % ntn) * 128;
    gemm_tile<SPLIT_A>(Ahi, Alo, Whi, Wlo, bias, C, m0, n0, ntn * 128, lds);
}

// three compacted GEMMs in one launch; blocks with m0 >= active rows exit
__global__ __launch_bounds__(512)
void step_gemm(const short* __restrict__ h0hi, const short* __restrict__ h0lo,
               const short* __restrict__ h1hi, const short* __restrict__ h1lo,
               const short* __restrict__ Whh0hi, const short* __restrict__ Whh0lo,
               const short* __restrict__ Wih1hi, const short* __restrict__ Wih1lo,
               const short* __restrict__ Whh1hi, const short* __restrict__ Whh1lo,
               float* __restrict__ gg0, float* __restrict__ ggX1, float* __restrict__ ggH1,
               const int* __restrict__ active, int i) {
    __shared__ short lds[16384];
    const int part = blockIdx.x / 192;
    const int bid = blockIdx.x % 192;
    const int m0 = (bid / 12) * 128, n0 = (bid % 12) * 128;
    if (part == 0) {
        const int act = active[i];
        if (m0 >= act) return;
        gemm_tile<true>(h0hi, h0lo, Whh0hi, Whh0lo, nullptr, gg0, m0, n0, H3, lds);
    } else if (part == 1) {
        if (i < 1) return;
        const int act = active[i - 1];
        if (m0 >= act) return;
        gemm_tile<true>(h0hi, h0lo, Wih1hi, Wih1lo, nullptr, ggX1, m0, n0, H3, lds);
    } else {
        if (i < 1) return;
        const int act = active[i - 1];
        if (m0 >= act) return;
        gemm_tile<true>(h1hi, h1lo, Whh1hi, Whh1lo, nullptr, ggH1, m0, n0, H3, lds);
    }
}

// ---------- elementwise GRU cells (compacted rows, in-place h update) ----------
// NOTE: xp0P is in COMPACT (permuted) row order -> indexed by m directly.
__global__ __launch_bounds__(256)
void cell_step(const float* __restrict__ gg0, const float* __restrict__ ggX1,
               const float* __restrict__ ggH1, const float* __restrict__ xp0P,
               const float* __restrict__ bhh0, const float* __restrict__ bih1,
               const float* __restrict__ bhh1,
               short* __restrict__ h0hi, short* __restrict__ h0lo,
               short* __restrict__ h1hi, short* __restrict__ h1lo,
               short* __restrict__ sel_h,
               const int* __restrict__ startsP,
               const int* __restrict__ active, int i) {
    const int part = blockIdx.x >> 10;
    const int idx = (((blockIdx.x & 1023) * 256) + threadIdx.x) * 4;
    const int m = idx >> 9;     // compact row
    const int j = idx & 511;
    if (part == 0) {
        const int act = active[i];
        if (m >= act) return;
        float4 gr = *(const float4*)&gg0[(size_t)m * H3 + j];
        float4 gz = *(const float4*)&gg0[(size_t)m * H3 + 512 + j];
        float4 gn = *(const float4*)&gg0[(size_t)m * H3 + 1024 + j];
        float4 xr = *(const float4*)&xp0P[(size_t)m * H3 + j];
        float4 xz = *(const float4*)&xp0P[(size_t)m * H3 + 512 + j];
        float4 xn = *(const float4*)&xp0P[(size_t)m * H3 + 1024 + j];
        short4 hh = *(const short4*)&h0hi[(size_t)m * Hd + j];
        short4 hl = *(const short4*)&h0lo[(size_t)m * Hd + j];
        float grv[4] = {gr.x, gr.y, gr.z, gr.w}, gzv[4] = {gz.x, gz.y, gz.z, gz.w}, gnv[4] = {gn.x, gn.y, gn.z, gn.w};
        float xrv[4] = {xr.x, xr.y, xr.z, xr.w}, xzv[4] = {xz.x, xz.y, xz.z, xz.w}, xnv[4] = {xn.x, xn.y, xn.z, xn.w};
        short hhv[4] = {hh.x, hh.y, hh.z, hh.w}, hlv[4] = {hl.x, hl.y, hl.z, hl.w};
        short nh[4], nl[4];
        #pragma unroll
        for (int c = 0; c < 4; ++c) {
            float hp = bf2f(hhv[c]) + bf2f(hlv[c]);
            float r = sigm(xrv[c] + grv[c] + bhh0[j + c]);
            float z = sigm(xzv[c] + gzv[c] + bhh0[512 + j + c]);
            float n = tanhf(xnv[c] + r * (gnv[c] + bhh0[1024 + j + c]));
            float h = (1.0f - z) * n + z * hp;
            nh[c] = f2bf(h);
            nl[c] = f2bf(h - bf2f(nh[c]));
        }
        *(short4*)&h0hi[(size_t)m * Hd + j] = make_short4(nh[0], nh[1], nh[2], nh[3]);
        *(short4*)&h0lo[(size_t)m * Hd + j] = make_short4(nl[0], nl[1], nl[2], nl[3]);
    } else {
        if (i < 1) return;
        const int act = active[i - 1];
        if (m >= act) return;
        const int t = i - 1;
        float4 ar = *(const float4*)&ggX1[(size_t)m * H3 + j];
        float4 az = *(const float4*)&ggX1[(size_t)m * H3 + 512 + j];
        float4 an = *(const float4*)&ggX1[(size_t)m * H3 + 1024 + j];
        float4 br = *(const float4*)&ggH1[(size_t)m * H3 + j];
        float4 bz = *(const float4*)&ggH1[(size_t)m * H3 + 512 + j];
        float4 bn = *(const float4*)&ggH1[(size_t)m * H3 + 1024 + j];
        short4 hh = *(const short4*)&h1hi[(size_t)m * Hd + j];
        short4 hl = *(const short4*)&h1lo[(size_t)m * Hd + j];
        float arv[4] = {ar.x, ar.y, ar.z, ar.w}, azv[4] = {az.x, az.y, az.z, az.w}, anv[4] = {an.x, an.y, an.z, an.w};
        float brv[4] = {br.x, br.y, br.z, br.w}, bzv[4] = {bz.x, bz.y, bz.z, bz.w}, bnv[4] = {bn.x, bn.y, bn.z, bn.w};
        short hhv[4] = {hh.x, hh.y, hh.z, hh.w}, hlv[4] = {hl.x, hl.y, hl.z, hl.w};
        short nh[4], nl[4], sb[4];
        #pragma unroll
        for (int c = 0; c < 4; ++c) {
            float hp = bf2f(hhv[c]) + bf2f(hlv[c]);
            float r = sigm(arv[c] + bih1[j + c] + brv[c] + bhh1[j + c]);
            float z = sigm(azv[c] + bih1[512 + j + c] + bzv[c] + bhh1[512 + j + c]);
            float n = tanhf(anv[c] + bih1[1024 + j + c] + r * (bnv[c] + bhh1[1024 + j + c]));
            float h = (1.0f - z) * n + z * hp;
            nh[c] = f2bf(h);
            nl[c] = f2bf(h - bf2f(nh[c]));
            sb[c] = f2bf(h);
        }
        *(short4*)&h1hi[(size_t)m * Hd + j] = make_short4(nh[0], nh[1], nh[2], nh[3]);
        *(short4*)&h1lo[(size_t)m * Hd + j] = make_short4(nl[0], nl[1], nl[2], nl[3]);
        size_t orow = (size_t)startsP[m] + t;   // prefix property: always valid here
        *(short4*)&sel_h[orow * Hd + j] = make_short4(sb[0], sb[1], sb[2], sb[3]);
    }
}

extern "C" void kernel_launch(void* const* d_in, const int* in_sizes, int n_in,
                              void* d_out, int out_size, void* d_ws, size_t ws_size,
                              hipStream_t stream) {
    (void)in_sizes; (void)n_in; (void)out_size; (void)ws_size;
    const float* x    = (const float*)d_in[0];
    const float* Wih0 = (const float*)d_in[1];
    const float* Whh0 = (const float*)d_in[2];
    const float* bih0 = (const float*)d_in[3];
    const float* bhh0 = (const float*)d_in[4];
    const float* Wih1 = (const float*)d_in[5];
    const float* Whh1 = (const float*)d_in[6];
    const float* bih1 = (const float*)d_in[7];
    const float* bhh1 = (const float*)d_in[8];
    const float* Wout = (const float*)d_in[9];
    const float* bout = (const float*)d_in[10];
    const int*   psi  = (const int*)d_in[11];
    float* out = (float*)d_out;

    char* p = (char*)d_ws;
    auto alloc = [&](size_t bytes) { char* r = p; p += (bytes + 255) & ~255ULL; return r; };
    short* xPhi   = (short*)alloc((size_t)Bn * Kd * 2);
    short* xPlo   = (short*)alloc((size_t)Bn * Kd * 2);
    short* Wih0hi = (short*)alloc((size_t)H3 * Kd * 2);
    short* Wih0lo = (short*)alloc((size_t)H3 * Kd * 2);
    short* Whh0hi = (short*)alloc((size_t)H3 * Kd * 2);
    short* Whh0lo = (short*)alloc((size_t)H3 * Kd * 2);
    short* Wih1hi = (short*)alloc((size_t)H3 * Kd * 2);
    short* Wih1lo = (short*)alloc((size_t)H3 * Kd * 2);
    short* Whh1hi = (short*)alloc((size_t)H3 * Kd * 2);
    short* Whh1lo = (short*)alloc((size_t)H3 * Kd * 2);
    short* Wouthi = (short*)alloc((size_t)OUTD * Kd * 2);
    short* Woutlo = (short*)alloc((size_t)OUTD * Kd * 2);
    float* xp0P   = (float*)alloc((size_t)Bn * H3 * 4);
    float* gg0    = (float*)alloc((size_t)Bn * H3 * 4);
    float* ggX1   = (float*)alloc((size_t)Bn * H3 * 4);
    float* ggH1   = (float*)alloc((size_t)Bn * H3 * 4);
    short* h0hi   = (short*)alloc((size_t)Bn * Hd * 2);
    short* h0lo   = (short*)alloc((size_t)Bn * Hd * 2);
    short* h1hi   = (short*)alloc((size_t)Bn * Hd * 2);
    short* h1lo   = (short*)alloc((size_t)Bn * Hd * 2);
    short* sel_h  = (short*)alloc((size_t)Nn * Hd * 2);
    int* perm     = (int*)alloc(Bn * 4);
    int* startsP  = (int*)alloc(Bn * 4);
    int* active   = (int*)alloc(64 * 4);

    prologue<<<1, 1024, 0, stream>>>(psi, perm, startsP, active);
    split_perm<<<1024, 256, 0, stream>>>(x, perm, xPhi, xPlo);
    split_kern<<<768, 256, 0, stream>>>(Wih0, Wih0hi, Wih0lo, H3 * Kd);
    split_kern<<<768, 256, 0, stream>>>(Whh0, Whh0hi, Whh0lo, H3 * Kd);
    split_kern<<<768, 256, 0, stream>>>(Wih1, Wih1hi, Wih1lo, H3 * Kd);
    split_kern<<<768, 256, 0, stream>>>(Whh1, Whh1hi, Whh1lo, H3 * Kd);
    split_kern<<<128, 256, 0, stream>>>(Wout, Wouthi, Woutlo, OUTD * Kd);
    zeroh<<<1024, 256, 0, stream>>>(h0hi, h0lo, h1hi, h1lo);

    // xp0P = xP @ Wih0^T + bih0  (compact row order)
    gemm_one<true><<<192, 512, 0, stream>>>(xPhi, xPlo, Wih0hi, Wih0lo, bih0, xp0P, 12);

    for (int i = 0; i <= TMAX; ++i) {
        step_gemm<<<576, 512, 0, stream>>>(h0hi, h0lo, h1hi, h1lo,
                                           Whh0hi, Whh0lo, Wih1hi, Wih1lo, Whh1hi, Whh1lo,
                                           gg0, ggX1, ggH1, active, i);
        cell_step<<<2048, 256, 0, stream>>>(gg0, ggX1, ggH1, xp0P,
                                            bhh0, bih1, bhh1,
                                            h0hi, h0lo, h1hi, h1lo,
                                            sel_h, startsP, active, i);
    }

    gemm_one<false><<<512, 512, 0, stream>>>(sel_h, nullptr, Wouthi, Woutlo, bout, out, 2);
}